// Round 2
// baseline (8895.703 us; speedup 1.0000x reference)
//
#include <hip/hip_runtime.h>
#include <stdint.h>

// GRU acoustic model, fp32 I/O (R2: inputs/outputs are float32 — R1's NaN was
// fp32 buffers read as bf16).
// Architecture: encoder recurrence distributed over 4 batch-groups x 19
// hidden-slices = 76 single-wave WGs, all co-resident. Whh/Wih bf16 B-frags
// register-resident (132 VGPRs). Per step: poll slice flags (agent atomics)
// -> acquire fence -> load h tile (bf16, global) -> 33 MFMAs -> gates fp32
// (own h carried fp32 in regs) -> publish h slice (bf16) -> release fence ->
// flag=t. Double-buffered by step parity.
// fc fused at end (MFMA, fp32 epilogue -> out). Decoder: 1 wave per batch,
// fully fp32 scalar+shuffle 13-dim GRU with constant input.
#define FEAT 13
#define EMB 300
#define BATCH 64
#define TSTEPS 2048
#define KPAD 320
#define NSLICE 19
#define NGROUP 4
#define NWG (NGROUP * NSLICE)

typedef float  floatx4 __attribute__((ext_vector_type(4)));
typedef short  shortx8 __attribute__((ext_vector_type(8)));

// workspace layout (bytes)
#define WS_HBUF  0                    // [2][4][16][KPAD] bf16 = 81920
#define WS_FLAGS 81920                // 4 groups * 128B, 19 ints each
#define WS_CTR   82432                // 4 group counters, 64B apart
#define WS_END   82688

__device__ __forceinline__ uint16_t f2b(float f) {
  union { float f; uint32_t i; } c; c.f = f;
  uint32_t r = c.i + 0x7fffu + ((c.i >> 16) & 1u);
  return (uint16_t)(r >> 16);
}
__device__ __forceinline__ float sigf(float x) {
  return __builtin_amdgcn_rcpf(1.f + __expf(-x));
}
__device__ __forceinline__ float tanhf_(float x) {
  // 1 - 2/(1+e^{2x}); saturates correctly for large |x|
  return 1.f - 2.f * __builtin_amdgcn_rcpf(1.f + __expf(2.f * x));
}

__global__ void gru_init(uint8_t* __restrict__ ws) {
  uint32_t* w = (uint32_t*)ws;
  int stride = gridDim.x * blockDim.x;
  for (int i = blockIdx.x * blockDim.x + threadIdx.x; i < WS_END / 4; i += stride)
    w[i] = 0;
}

__launch_bounds__(64, 1)
__global__ void gru_main(const float* __restrict__ x,     // [64][2048][13]
                         const float* __restrict__ eWih,  // [900][13]
                         const float* __restrict__ eWhh,  // [900][300]
                         const float* __restrict__ ebih,  // [900]
                         const float* __restrict__ ebhh,  // [900]
                         const float* __restrict__ fcW,   // [300][300]
                         const float* __restrict__ fcb,   // [300]
                         const float* __restrict__ dWih,  // [39][300]
                         const float* __restrict__ dWhh,  // [39][13]
                         const float* __restrict__ dbih,  // [39]
                         const float* __restrict__ dbhh,  // [39]
                         float* __restrict__ out,         // fp32 outputs
                         uint8_t* __restrict__ ws) {
  __shared__ uint16_t lds_whh[3 * 16 * KPAD];  // Whh slice (bf16), padded K
  __shared__ uint16_t lds_wih[3 * 16 * 32];    // Wih slice (bf16), padded K
  __shared__ uint16_t lds_fcw[16 * KPAD];      // fc_W slice (bf16), padded K
  __shared__ uint16_t lds_xt[16 * 32];         // x_t tile (bf16), padded K

  const int lane = threadIdx.x;
  const int g = blockIdx.x / NSLICE;   // batch group (16 rows)
  const int s = blockIdx.x % NSLICE;   // hidden slice (16 cols)
  const int nl = lane & 15;            // MFMA row(A)/col(B,D)
  const int q  = lane >> 4;            // k-quad
  const int j  = 16 * s + nl;          // global hidden col
  const bool jv = (j < EMB);

  // ---- stage weight slices to LDS (one-time), fp32 -> bf16, zero-padded ----
  for (int i = lane; i < 3 * 16 * KPAD; i += 64) {
    int k = i % KPAD, rl = (i / KPAD) % 16, G = i / (16 * KPAD);
    int row = 16 * s + rl;
    lds_whh[i] = (k < EMB && row < EMB) ? f2b(eWhh[(G * EMB + row) * EMB + k]) : (uint16_t)0;
  }
  for (int i = lane; i < 3 * 16 * 32; i += 64) {
    int k = i % 32, rl = (i / 32) % 16, G = i / (16 * 32);
    int row = 16 * s + rl;
    lds_wih[i] = (k < FEAT && row < EMB) ? f2b(eWih[(G * EMB + row) * FEAT + k]) : (uint16_t)0;
  }
  for (int i = lane; i < 16 * KPAD; i += 64) {
    int k = i % KPAD, rl = i / KPAD;
    int row = 16 * s + rl;
    lds_fcw[i] = (k < EMB && row < EMB) ? f2b(fcW[row * EMB + k]) : (uint16_t)0;
  }
  for (int i = lane; i < 16 * 32; i += 64) lds_xt[i] = 0;
  __syncthreads();

  // ---- weights -> register B-fragments (persist across all 2048 steps) ----
  shortx8 Bh0[10], Bh1[10], Bh2[10];
#pragma unroll
  for (int kt = 0; kt < 10; ++kt) {
    Bh0[kt] = *(const shortx8*)(lds_whh + (0 * 16 + nl) * KPAD + kt * 32 + q * 8);
    Bh1[kt] = *(const shortx8*)(lds_whh + (1 * 16 + nl) * KPAD + kt * 32 + q * 8);
    Bh2[kt] = *(const shortx8*)(lds_whh + (2 * 16 + nl) * KPAD + kt * 32 + q * 8);
  }
  shortx8 Bx0 = *(const shortx8*)(lds_wih + (0 * 16 + nl) * 32 + q * 8);
  shortx8 Bx1 = *(const shortx8*)(lds_wih + (1 * 16 + nl) * 32 + q * 8);
  shortx8 Bx2 = *(const shortx8*)(lds_wih + (2 * 16 + nl) * 32 + q * 8);

  float b_r = 0.f, b_z = 0.f, bi_n = 0.f, bh_n = 0.f, fcbv = 0.f;
  if (jv) {
    b_r  = ebih[j] + ebhh[j];
    b_z  = ebih[EMB + j] + ebhh[EMB + j];
    bi_n = ebih[2 * EMB + j];
    bh_n = ebhh[2 * EMB + j];
    fcbv = fcb[j];
  }

  uint16_t* hbuf  = (uint16_t*)(ws + WS_HBUF);
  int*      flags = (int*)(ws + WS_FLAGS + (g << 7));
  float*    oemb  = out + (size_t)BATCH * TSTEPS * FEAT;  // emb region of out

  float hprev[4] = {0.f, 0.f, 0.f, 0.f};  // fp32 carry of own (row,col) h

  // ================= encoder recurrence =================
  for (int t = 1; t <= TSTEPS; ++t) {
    const int pp = (t - 1) & 1, pn = t & 1;

    // stage x_{t-1} tile, fp32 -> bf16 (no flag dependency -> overlaps poll)
    for (int i = lane; i < 16 * FEAT; i += 64) {
      int m = i / FEAT, f = i - m * FEAT;
      lds_xt[m * 32 + f] = f2b(x[((g * 16 + m) * TSTEPS + (t - 1)) * FEAT + f]);
    }

    if (t > 1) {
      if (lane < NSLICE) {
        while (__hip_atomic_load(flags + lane, __ATOMIC_RELAXED,
                                 __HIP_MEMORY_SCOPE_AGENT) < t - 1) {}
      }
      __builtin_amdgcn_fence(__ATOMIC_ACQUIRE, "agent");
    }
    __syncthreads();

    // A fragments: h_{t-1} (global, cross-WG, bf16) + x_t (LDS)
    const uint16_t* hrow = hbuf + ((pp * NGROUP + g) * 16 + nl) * KPAD;
    shortx8 A[10];
#pragma unroll
    for (int kt = 0; kt < 10; ++kt)
      A[kt] = *(const shortx8*)(hrow + kt * 32 + q * 8);
    shortx8 Axf = *(const shortx8*)(lds_xt + nl * 32 + q * 8);

    floatx4 ar = {0.f, 0.f, 0.f, 0.f}, az = {0.f, 0.f, 0.f, 0.f};
    floatx4 an = {0.f, 0.f, 0.f, 0.f}, ax = {0.f, 0.f, 0.f, 0.f};
#pragma unroll
    for (int kt = 0; kt < 10; ++kt) {
      ar = __builtin_amdgcn_mfma_f32_16x16x32_bf16(A[kt], Bh0[kt], ar, 0, 0, 0);
      az = __builtin_amdgcn_mfma_f32_16x16x32_bf16(A[kt], Bh1[kt], az, 0, 0, 0);
      an = __builtin_amdgcn_mfma_f32_16x16x32_bf16(A[kt], Bh2[kt], an, 0, 0, 0);
    }
    ar = __builtin_amdgcn_mfma_f32_16x16x32_bf16(Axf, Bx0, ar, 0, 0, 0);
    az = __builtin_amdgcn_mfma_f32_16x16x32_bf16(Axf, Bx1, az, 0, 0, 0);
    ax = __builtin_amdgcn_mfma_f32_16x16x32_bf16(Axf, Bx2, ax, 0, 0, 0);

    // gates (fp32) + publish slice (agent-scope 2B atomic stores)
    uint16_t* dst = hbuf + ((pn * NGROUP + g) * 16 + q * 4) * KPAD + j;
#pragma unroll
    for (int i = 0; i < 4; ++i) {
      float r = sigf(ar[i] + b_r);
      float z = sigf(az[i] + b_z);
      float n = tanhf_(ax[i] + bi_n + r * (an[i] + bh_n));
      float h = z * (hprev[i] - n) + n;
      h = jv ? h : 0.f;  // keep K-pad region zero
      hprev[i] = h;
      __hip_atomic_store(dst + i * KPAD, f2b(h), __ATOMIC_RELAXED,
                         __HIP_MEMORY_SCOPE_AGENT);
    }
    __builtin_amdgcn_fence(__ATOMIC_RELEASE, "agent");
    if (lane == 0)
      __hip_atomic_store(flags + s, t, __ATOMIC_RELAXED, __HIP_MEMORY_SCOPE_AGENT);
  }

  // ================= fc: emb = relu(h_T @ fcW^T + fcb) =================
  if (lane < NSLICE) {
    while (__hip_atomic_load(flags + lane, __ATOMIC_RELAXED,
                             __HIP_MEMORY_SCOPE_AGENT) < TSTEPS) {}
  }
  __builtin_amdgcn_fence(__ATOMIC_ACQUIRE, "agent");
  {
    const uint16_t* hrowT = hbuf + ((0 * NGROUP + g) * 16 + nl) * KPAD;  // T even
    floatx4 ae = {0.f, 0.f, 0.f, 0.f};
#pragma unroll
    for (int kt = 0; kt < 10; ++kt) {
      shortx8 a   = *(const shortx8*)(hrowT + kt * 32 + q * 8);
      shortx8 bfc = *(const shortx8*)(lds_fcw + nl * KPAD + kt * 32 + q * 8);
      ae = __builtin_amdgcn_mfma_f32_16x16x32_bf16(a, bfc, ae, 0, 0, 0);
    }
#pragma unroll
    for (int i = 0; i < 4; ++i) {
      float e = ae[i] + fcbv;
      e = e > 0.f ? e : 0.f;
      if (jv) {
        int b = g * 16 + q * 4 + i;
        // emb is both output 1 and the decoder's input; single fp32 write path
        __hip_atomic_store(oemb + b * EMB + j, e, __ATOMIC_RELAXED,
                           __HIP_MEMORY_SCOPE_AGENT);
      }
    }
  }
  __builtin_amdgcn_fence(__ATOMIC_RELEASE, "agent");
  if (lane == 0)
    __hip_atomic_fetch_add((int*)(ws + WS_CTR) + (g << 4), 1, __ATOMIC_RELAXED,
                           __HIP_MEMORY_SCOPE_AGENT);

  // ================= decoder: one wave per batch, all fp32 =================
  const int b = blockIdx.x;
  if (b >= BATCH) return;
  {
    const int* cp = (const int*)(ws + WS_CTR) + ((b >> 4) << 4);
    while (__hip_atomic_load(cp, __ATOMIC_RELAXED, __HIP_MEMORY_SCOPE_AGENT) < NSLICE) {}
  }
  __builtin_amdgcn_fence(__ATOMIC_ACQUIRE, "agent");

  const int lj = lane;                      // gate-lane: [0,13)=r [13,26)=z [26,39)=n
  float Wd[FEAT];
#pragma unroll
  for (int k = 0; k < FEAT; ++k) Wd[k] = 0.f;
  float bhhv = 0.f, dgi = 0.f;
  if (lj < 3 * FEAT) {
#pragma unroll
    for (int k = 0; k < FEAT; ++k) Wd[k] = dWhh[lj * FEAT + k];
    bhhv = dbhh[lj];
    dgi  = dbih[lj];
    const float* er = oemb + b * EMB;
#pragma unroll 4
    for (int k = 0; k < EMB; ++k)
      dgi = fmaf(er[k], dWih[lj * EMB + k], dgi);
  }

  float hrep[FEAT];
#pragma unroll
  for (int k = 0; k < FEAT; ++k) hrep[k] = 0.f;
  float hown = 0.f;  // lanes 26..38 own h[lj-26]
  const bool nlane = (lj >= 2 * FEAT && lj < 3 * FEAT);
  float* orow = out + (size_t)b * TSTEPS * FEAT;

  for (int t = 0; t < TSTEPS; ++t) {
    float gh = bhhv;
#pragma unroll
    for (int k = 0; k < FEAT; ++k) gh = fmaf(Wd[k], hrep[k], gh);
    float sg = sigf(dgi + gh);                     // r on lanes 0..12, z on 13..25
    float rr = __shfl(sg, (lj - 2 * FEAT) & 63);   // n-lanes fetch r
    float zz = __shfl(sg, (lj - FEAT) & 63);       // n-lanes fetch z
    float nn = tanhf_(dgi + rr * gh);
    float hn = zz * (hown - nn) + nn;
    bool same = (!nlane) || (hn == hown);
    if (nlane) {
      orow[t * FEAT + (lj - 2 * FEAT)] = hn;
      hown = hn;
    }
#pragma unroll
    for (int k = 0; k < FEAT; ++k) hrep[k] = __shfl(hown, 2 * FEAT + k);
    if (__all(same)) {  // exact fp32 fixed point -> remaining outputs constant
      if (nlane) {
        for (int t2 = t + 1; t2 < TSTEPS; ++t2)
          orow[t2 * FEAT + (lj - 2 * FEAT)] = hn;
      }
      break;
    }
  }
}

extern "C" void kernel_launch(void* const* d_in, const int* in_sizes, int n_in,
                              void* d_out, int out_size, void* d_ws, size_t ws_size,
                              hipStream_t stream) {
  (void)in_sizes; (void)n_in; (void)out_size; (void)ws_size;
  const float* x    = (const float*)d_in[0];
  const float* eWih = (const float*)d_in[1];
  const float* eWhh = (const float*)d_in[2];
  const float* ebih = (const float*)d_in[3];
  const float* ebhh = (const float*)d_in[4];
  const float* fcW  = (const float*)d_in[5];
  const float* fcb  = (const float*)d_in[6];
  const float* dWih = (const float*)d_in[7];
  const float* dWhh = (const float*)d_in[8];
  const float* dbih = (const float*)d_in[9];
  const float* dbhh = (const float*)d_in[10];

  hipLaunchKernelGGL(gru_init, dim3(32), dim3(256), 0, stream, (uint8_t*)d_ws);
  hipLaunchKernelGGL(gru_main, dim3(NWG), dim3(64), 0, stream,
                     x, eWih, eWhh, ebih, ebhh, fcW, fcb, dWih, dWhh, dbih, dbhh,
                     (float*)d_out, (uint8_t*)d_ws);
}

// Round 3
// 7200.313 us; speedup vs baseline: 1.2355x; 1.2355x over previous
//
#include <hip/hip_runtime.h>
#include <stdint.h>

// GRU acoustic model, fp32 I/O. R3: fence-free cross-WG exchange.
// R2 post-mortem: agent acquire/release fences = buffer_inv/buffer_wbl2 sc1
// (full L2 inv/writeback) twice per step -> 10.4K cyc/step, FETCH 362MB.
// R3: every exchanged h word is a self-validating u32 (step_tag<<16 | bf16).
// Relaxed agent atomics only (sc0 sc1 -> L3 coherence point). Readers poll
// their own A-frag words until all tags==t-1; no flags, no fences, no
// writer-side ordering (double buffer by parity + tag check make in-flight
// stores harmless; writer's poll vmcnt drains its own prior-step stores
// before buffer reuse).
#define FEAT 13
#define EMB 300
#define BATCH 64
#define TSTEPS 2048
#define KPAD 320
#define KTAG 304            // 19*16 cols written by slices; 304..319 = tagged pad
#define NSLICE 19
#define NGROUP 4
#define NWG (NGROUP * NSLICE)

typedef float  floatx4 __attribute__((ext_vector_type(4)));
typedef short  shortx8 __attribute__((ext_vector_type(8)));

// workspace layout (bytes)
#define WS_HBUF 0                    // u32[2][4][16][KPAD] = 163840
#define WS_CTR  163840               // 4 group counters, 64B apart
#define WS_END  164096

__device__ __forceinline__ uint16_t f2b(float f) {
  union { float f; uint32_t i; } c; c.f = f;
  uint32_t r = c.i + 0x7fffu + ((c.i >> 16) & 1u);
  return (uint16_t)(r >> 16);
}
__device__ __forceinline__ float sigf(float x) {
  return __builtin_amdgcn_rcpf(1.f + __expf(-x));
}
__device__ __forceinline__ float tanhf_(float x) {
  return 1.f - 2.f * __builtin_amdgcn_rcpf(1.f + __expf(2.f * x));
}

__global__ void gru_init(uint8_t* __restrict__ ws) {
  uint32_t* w = (uint32_t*)ws;
  int stride = gridDim.x * blockDim.x;
  for (int i = blockIdx.x * blockDim.x + threadIdx.x; i < WS_END / 4; i += stride)
    w[i] = 0;   // tag 0 == "step 0 ready, h=0" -> t=1 needs no special case
}

__launch_bounds__(64, 1)
__global__ void gru_main(const float* __restrict__ x,     // [64][2048][13]
                         const float* __restrict__ eWih,  // [900][13]
                         const float* __restrict__ eWhh,  // [900][300]
                         const float* __restrict__ ebih,  // [900]
                         const float* __restrict__ ebhh,  // [900]
                         const float* __restrict__ fcW,   // [300][300]
                         const float* __restrict__ fcb,   // [300]
                         const float* __restrict__ dWih,  // [39][300]
                         const float* __restrict__ dWhh,  // [39][13]
                         const float* __restrict__ dbih,  // [39]
                         const float* __restrict__ dbhh,  // [39]
                         float* __restrict__ out,         // fp32 outputs
                         uint8_t* __restrict__ ws) {
  __shared__ uint16_t lds_whh[3 * 16 * KPAD];  // Whh slice (bf16)
  __shared__ uint16_t lds_wih[3 * 16 * 32];    // Wih slice (bf16)
  __shared__ uint16_t lds_fcw[16 * KPAD];      // fc_W slice (bf16)
  __shared__ uint16_t lds_xt[16 * 32];         // x_t tile (bf16)

  const int lane = threadIdx.x;
  const int g = blockIdx.x / NSLICE;   // batch group (16 rows)
  const int s = blockIdx.x % NSLICE;   // hidden slice (16 cols)
  const int nl = lane & 15;            // MFMA row(A)/col(B,D)
  const int q  = lane >> 4;            // k-quad
  const int j  = 16 * s + nl;          // global hidden col
  const bool jv = (j < EMB);

  // ---- stage weight slices to LDS (one-time), fp32 -> bf16, zero-padded ----
  for (int i = lane; i < 3 * 16 * KPAD; i += 64) {
    int k = i % KPAD, rl = (i / KPAD) % 16, G = i / (16 * KPAD);
    int row = 16 * s + rl;
    lds_whh[i] = (k < EMB && row < EMB) ? f2b(eWhh[(G * EMB + row) * EMB + k]) : (uint16_t)0;
  }
  for (int i = lane; i < 3 * 16 * 32; i += 64) {
    int k = i % 32, rl = (i / 32) % 16, G = i / (16 * 32);
    int row = 16 * s + rl;
    lds_wih[i] = (k < FEAT && row < EMB) ? f2b(eWih[(G * EMB + row) * FEAT + k]) : (uint16_t)0;
  }
  for (int i = lane; i < 16 * KPAD; i += 64) {
    int k = i % KPAD, rl = i / KPAD;
    int row = 16 * s + rl;
    lds_fcw[i] = (k < EMB && row < EMB) ? f2b(fcW[row * EMB + k]) : (uint16_t)0;
  }
  for (int i = lane; i < 16 * 32; i += 64) lds_xt[i] = 0;
  __syncthreads();

  // ---- weights -> register B-fragments (persist across all 2048 steps) ----
  shortx8 Bh0[10], Bh1[10], Bh2[10];
#pragma unroll
  for (int kt = 0; kt < 10; ++kt) {
    Bh0[kt] = *(const shortx8*)(lds_whh + (0 * 16 + nl) * KPAD + kt * 32 + q * 8);
    Bh1[kt] = *(const shortx8*)(lds_whh + (1 * 16 + nl) * KPAD + kt * 32 + q * 8);
    Bh2[kt] = *(const shortx8*)(lds_whh + (2 * 16 + nl) * KPAD + kt * 32 + q * 8);
  }
  shortx8 Bx0 = *(const shortx8*)(lds_wih + (0 * 16 + nl) * 32 + q * 8);
  shortx8 Bx1 = *(const shortx8*)(lds_wih + (1 * 16 + nl) * 32 + q * 8);
  shortx8 Bx2 = *(const shortx8*)(lds_wih + (2 * 16 + nl) * 32 + q * 8);

  float b_r = 0.f, b_z = 0.f, bi_n = 0.f, bh_n = 0.f, fcbv = 0.f;
  if (jv) {
    b_r  = ebih[j] + ebhh[j];
    b_z  = ebih[EMB + j] + ebhh[EMB + j];
    bi_n = ebih[2 * EMB + j];
    bh_n = ebhh[2 * EMB + j];
    fcbv = fcb[j];
  }

  uint32_t* hbufT = (uint32_t*)(ws + WS_HBUF);
  float*    oemb  = out + (size_t)BATCH * TSTEPS * FEAT;  // emb region of out

  float hprev[4] = {0.f, 0.f, 0.f, 0.f};
  unsigned long long dv[40];
  shortx8 A[10];

  // ================= encoder recurrence =================
  for (int t = 1; t <= TSTEPS; ++t) {
    const int pp = (t - 1) & 1, pn = t & 1;

    // stage x_{t-1} tile (ordinary cached loads; overlaps the poll below)
    for (int i = lane; i < 16 * FEAT; i += 64) {
      int m = i / FEAT, f = i - m * FEAT;
      lds_xt[m * 32 + f] = f2b(x[((g * 16 + m) * TSTEPS + (t - 1)) * FEAT + f]);
    }

    // ---- tagged poll+load: retry until every word carries tag t-1 ----
    const unsigned long long* hrow64 =
        (const unsigned long long*)(hbufT + ((pp * NGROUP + g) * 16 + nl) * KPAD) + q * 4;
    const unsigned long long TT =
        (((unsigned long long)(t - 1)) << 16) | (((unsigned long long)(t - 1)) << 48);
    while (true) {
#pragma unroll
      for (int kt = 0; kt < 10; ++kt) {
#pragma unroll
        for (int w = 0; w < 4; ++w)
          dv[kt * 4 + w] = __hip_atomic_load(hrow64 + kt * 16 + w, __ATOMIC_RELAXED,
                                             __HIP_MEMORY_SCOPE_AGENT);
      }
      unsigned long long acc = 0;
#pragma unroll
      for (int i = 0; i < 40; ++i) acc |= (dv[i] ^ TT);
      if (__all((acc & 0xFFFF0000FFFF0000ULL) == 0ULL)) break;
    }
    // unpack tagged u32 pairs -> bf16 A-fragments (v_perm byte-select)
#pragma unroll
    for (int kt = 0; kt < 10; ++kt) {
      union { uint32_t u[4]; shortx8 v; } c;
#pragma unroll
      for (int w = 0; w < 4; ++w) {
        unsigned long long dd = dv[kt * 4 + w];
        c.u[w] = __builtin_amdgcn_perm((uint32_t)(dd >> 32), (uint32_t)dd, 0x05040100u);
      }
      A[kt] = c.v;
    }
    shortx8 Axf = *(const shortx8*)(lds_xt + nl * 32 + q * 8);

    floatx4 ar = {0.f, 0.f, 0.f, 0.f}, az = {0.f, 0.f, 0.f, 0.f};
    floatx4 an = {0.f, 0.f, 0.f, 0.f}, ax = {0.f, 0.f, 0.f, 0.f};
#pragma unroll
    for (int kt = 0; kt < 10; ++kt) {
      ar = __builtin_amdgcn_mfma_f32_16x16x32_bf16(A[kt], Bh0[kt], ar, 0, 0, 0);
      az = __builtin_amdgcn_mfma_f32_16x16x32_bf16(A[kt], Bh1[kt], az, 0, 0, 0);
      an = __builtin_amdgcn_mfma_f32_16x16x32_bf16(A[kt], Bh2[kt], an, 0, 0, 0);
    }
    ar = __builtin_amdgcn_mfma_f32_16x16x32_bf16(Axf, Bx0, ar, 0, 0, 0);
    az = __builtin_amdgcn_mfma_f32_16x16x32_bf16(Axf, Bx1, az, 0, 0, 0);
    ax = __builtin_amdgcn_mfma_f32_16x16x32_bf16(Axf, Bx2, ax, 0, 0, 0);

    // gates (fp32, own h carried in regs) + publish tagged words (no ordering)
    uint32_t* dst = hbufT + ((pn * NGROUP + g) * 16 + q * 4) * KPAD + j;
    const uint32_t tg = ((uint32_t)t) << 16;
#pragma unroll
    for (int i = 0; i < 4; ++i) {
      float r = sigf(ar[i] + b_r);
      float z = sigf(az[i] + b_z);
      float n = tanhf_(ax[i] + bi_n + r * (an[i] + bh_n));
      float h = z * (hprev[i] - n) + n;
      h = jv ? h : 0.f;
      hprev[i] = h;
      __hip_atomic_store(dst + i * KPAD, tg | (uint32_t)f2b(h), __ATOMIC_RELAXED,
                         __HIP_MEMORY_SCOPE_AGENT);
    }
    if (s == NSLICE - 1) {  // tag the K-pad words 304..319 so readers stay uniform
      uint32_t* dst2 = hbufT + ((pn * NGROUP + g) * 16 + q * 4) * KPAD + KTAG + nl;
#pragma unroll
      for (int i = 0; i < 4; ++i)
        __hip_atomic_store(dst2 + i * KPAD, tg, __ATOMIC_RELAXED,
                           __HIP_MEMORY_SCOPE_AGENT);
    }
  }

  // ================= fc: emb = relu(h_T @ fcW^T + fcb) =================
  {
    const unsigned long long* hrow64 =
        (const unsigned long long*)(hbufT + ((0 * NGROUP + g) * 16 + nl) * KPAD) + q * 4;  // T even
    const unsigned long long TT =
        (((unsigned long long)TSTEPS) << 16) | (((unsigned long long)TSTEPS) << 48);
    while (true) {
#pragma unroll
      for (int kt = 0; kt < 10; ++kt) {
#pragma unroll
        for (int w = 0; w < 4; ++w)
          dv[kt * 4 + w] = __hip_atomic_load(hrow64 + kt * 16 + w, __ATOMIC_RELAXED,
                                             __HIP_MEMORY_SCOPE_AGENT);
      }
      unsigned long long acc = 0;
#pragma unroll
      for (int i = 0; i < 40; ++i) acc |= (dv[i] ^ TT);
      if (__all((acc & 0xFFFF0000FFFF0000ULL) == 0ULL)) break;
    }
#pragma unroll
    for (int kt = 0; kt < 10; ++kt) {
      union { uint32_t u[4]; shortx8 v; } c;
#pragma unroll
      for (int w = 0; w < 4; ++w) {
        unsigned long long dd = dv[kt * 4 + w];
        c.u[w] = __builtin_amdgcn_perm((uint32_t)(dd >> 32), (uint32_t)dd, 0x05040100u);
      }
      A[kt] = c.v;
    }
    floatx4 ae = {0.f, 0.f, 0.f, 0.f};
#pragma unroll
    for (int kt = 0; kt < 10; ++kt) {
      shortx8 bfc = *(const shortx8*)(lds_fcw + nl * KPAD + kt * 32 + q * 8);
      ae = __builtin_amdgcn_mfma_f32_16x16x32_bf16(A[kt], bfc, ae, 0, 0, 0);
    }
#pragma unroll
    for (int i = 0; i < 4; ++i) {
      float e = ae[i] + fcbv;
      e = e > 0.f ? e : 0.f;
      if (jv) {
        int b = g * 16 + q * 4 + i;
        union { float f; uint32_t u; } cc; cc.f = e;
        __hip_atomic_store((uint32_t*)(oemb + b * EMB + j), cc.u, __ATOMIC_RELAXED,
                           __HIP_MEMORY_SCOPE_AGENT);
      }
    }
  }
  // emb stores are agent-scope (already at coherence point); drain then count
  asm volatile("s_waitcnt vmcnt(0)" ::: "memory");
  if (lane == 0)
    __hip_atomic_fetch_add((int*)(ws + WS_CTR) + (g << 4), 1, __ATOMIC_RELAXED,
                           __HIP_MEMORY_SCOPE_AGENT);

  // ================= decoder: one wave per batch, all fp32 =================
  const int b = blockIdx.x;
  if (b >= BATCH) return;
  {
    const int* cp = (const int*)(ws + WS_CTR) + ((b >> 4) << 4);
    while (__hip_atomic_load(cp, __ATOMIC_RELAXED, __HIP_MEMORY_SCOPE_AGENT) < NSLICE) {}
  }

  const int lj = lane;                      // [0,13)=r [13,26)=z [26,39)=n
  float Wd[FEAT];
#pragma unroll
  for (int k = 0; k < FEAT; ++k) Wd[k] = 0.f;
  float bhhv = 0.f, dgi = 0.f;
  if (lj < 3 * FEAT) {
#pragma unroll
    for (int k = 0; k < FEAT; ++k) Wd[k] = dWhh[lj * FEAT + k];
    bhhv = dbhh[lj];
    dgi  = dbih[lj];
    const uint32_t* er = (const uint32_t*)(oemb + b * EMB);
#pragma unroll 4
    for (int k = 0; k < EMB; ++k) {
      union { uint32_t u; float f; } cc;
      cc.u = __hip_atomic_load(er + k, __ATOMIC_RELAXED, __HIP_MEMORY_SCOPE_AGENT);
      dgi = fmaf(cc.f, dWih[lj * EMB + k], dgi);
    }
  }

  float hrep[FEAT];
#pragma unroll
  for (int k = 0; k < FEAT; ++k) hrep[k] = 0.f;
  float hown = 0.f;
  const bool nlane = (lj >= 2 * FEAT && lj < 3 * FEAT);
  float* orow = out + (size_t)b * TSTEPS * FEAT;

  for (int t = 0; t < TSTEPS; ++t) {
    float gh = bhhv;
#pragma unroll
    for (int k = 0; k < FEAT; ++k) gh = fmaf(Wd[k], hrep[k], gh);
    float sg = sigf(dgi + gh);
    float rr = __shfl(sg, (lj - 2 * FEAT) & 63);
    float zz = __shfl(sg, (lj - FEAT) & 63);
    float nn = tanhf_(dgi + rr * gh);
    float hn = zz * (hown - nn) + nn;
    bool same = (!nlane) || (hn == hown);
    if (nlane) {
      orow[t * FEAT + (lj - 2 * FEAT)] = hn;
      hown = hn;
    }
#pragma unroll
    for (int k = 0; k < FEAT; ++k) hrep[k] = __shfl(hown, 2 * FEAT + k);
    if (__all(same)) {
      if (nlane) {
        for (int t2 = t + 1; t2 < TSTEPS; ++t2)
          orow[t2 * FEAT + (lj - 2 * FEAT)] = hn;
      }
      break;
    }
  }
}

extern "C" void kernel_launch(void* const* d_in, const int* in_sizes, int n_in,
                              void* d_out, int out_size, void* d_ws, size_t ws_size,
                              hipStream_t stream) {
  (void)in_sizes; (void)n_in; (void)out_size; (void)ws_size;
  const float* x    = (const float*)d_in[0];
  const float* eWih = (const float*)d_in[1];
  const float* eWhh = (const float*)d_in[2];
  const float* ebih = (const float*)d_in[3];
  const float* ebhh = (const float*)d_in[4];
  const float* fcW  = (const float*)d_in[5];
  const float* fcb  = (const float*)d_in[6];
  const float* dWih = (const float*)d_in[7];
  const float* dWhh = (const float*)d_in[8];
  const float* dbih = (const float*)d_in[9];
  const float* dbhh = (const float*)d_in[10];

  hipLaunchKernelGGL(gru_init, dim3(32), dim3(256), 0, stream, (uint8_t*)d_ws);
  hipLaunchKernelGGL(gru_main, dim3(NWG), dim3(64), 0, stream,
                     x, eWih, eWhh, ebih, ebhh, fcW, fcb, dWih, dWhh, dbih, dbhh,
                     (float*)d_out, (uint8_t*)d_ws);
}